// Round 11
// baseline (736.690 us; speedup 1.0000x reference)
//
#include <hip/hip_runtime.h>
#include <math.h>

constexpr int N_NODES = 500000;
constexpr int N_EDGES = 8000000;
constexpr int IN_DIM = 10, HID_DIM = 35, OUT_DIM = 2;

constexpr int BUCKET_BITS = 11;                       // 2048 dst-nodes per bucket
constexpr int BNODES = 1 << BUCKET_BITS;              // 2048
constexpr int NB = (N_NODES + BNODES - 1) / BNODES;   // 245 buckets
constexpr int NBP = 256;                              // padded
constexpr int NSLOT = NB * BNODES;                    // 501760 descriptor slots

constexpr int PART_TPB = 1024;
constexpr int EPT = 32;
constexpr int TILE = PART_TPB * EPT;                  // 32768
constexpr int NTILES = (N_EDGES + TILE - 1) / TILE;   // 245

__device__ __forceinline__ unsigned umin(unsigned a, unsigned b) { return a < b ? a : b; }

// ---------------- zero bucket counters ----------------
__global__ void zero_small_kernel(unsigned* __restrict__ bcount) {
    bcount[threadIdx.x] = 0u;
}

// ---------------- histogram: edges per dst-bucket (245 bins), int4 loads ------
__global__ void hist_kernel(const int4* __restrict__ dst4, unsigned* __restrict__ bcount,
                            int E4) {
    __shared__ unsigned h[NBP];
    h[threadIdx.x] = 0u;
    __syncthreads();
    int stride = gridDim.x * blockDim.x;
    for (int e = blockIdx.x * blockDim.x + threadIdx.x; e < E4; e += stride) {
        int4 v = dst4[e];
        atomicAdd(&h[v.x >> BUCKET_BITS], 1u);
        atomicAdd(&h[v.y >> BUCKET_BITS], 1u);
        atomicAdd(&h[v.z >> BUCKET_BITS], 1u);
        atomicAdd(&h[v.w >> BUCKET_BITS], 1u);
    }
    __syncthreads();
    if (h[threadIdx.x]) atomicAdd(&bcount[threadIdx.x], h[threadIdx.x]);
}

// ---------------- exclusive scan of bucket counts (1 block, 256) -------------
__global__ void scan_kernel(const unsigned* __restrict__ bcount,
                            unsigned* __restrict__ bbase, unsigned* __restrict__ bcursor) {
    __shared__ unsigned s[NBP];
    int t = threadIdx.x;
    unsigned v = bcount[t];
    s[t] = v; __syncthreads();
    for (int off = 1; off < NBP; off <<= 1) {
        unsigned a = (t >= off) ? s[t - off] : 0u;
        __syncthreads();
        s[t] += a;
        __syncthreads();
    }
    bbase[t] = s[t] - v;  bcursor[t] = s[t] - v;
    if (t == 0) bbase[NBP] = (unsigned)N_EDGES;
}

// ---------------- partition: pack (src<<11 | dst&2047) grouped by bucket ------
__global__ __launch_bounds__(PART_TPB) void partition_kernel(
        const int* __restrict__ src, const int* __restrict__ dst,
        unsigned* __restrict__ bcursor, unsigned* __restrict__ packed, int E) {
    __shared__ unsigned h[NBP], base[NBP], c2[NBP];
    int t = threadIdx.x;
    for (int k = t; k < NBP; k += PART_TPB) { h[k] = 0u; c2[k] = 0u; }
    __syncthreads();
    int tile0 = blockIdx.x * TILE;
    int d[EPT];
    #pragma unroll
    for (int q = 0; q < EPT; ++q) {
        int e = tile0 + q * PART_TPB + t;
        d[q] = (e < E) ? dst[e] : -1;
        if (d[q] >= 0) atomicAdd(&h[d[q] >> BUCKET_BITS], 1u);
    }
    __syncthreads();
    for (int k = t; k < NBP; k += PART_TPB)
        if (h[k]) base[k] = atomicAdd(&bcursor[k], h[k]);
    __syncthreads();
    #pragma unroll
    for (int q = 0; q < EPT; ++q) {
        int e = tile0 + q * PART_TPB + t;
        if (d[q] >= 0) {
            int b = d[q] >> BUCKET_BITS;
            unsigned pos = base[b] + atomicAdd(&c2[b], 1u);
            packed[pos] = ((unsigned)src[e] << BUCKET_BITS) | (unsigned)(d[q] & (BNODES - 1));
        }
    }
}

// ---------------- per-bucket CSR build + degree-sorted descriptors ------------
// desc[slot] = {rowbeg, node<<13 | deg}, slots within a bucket sorted by degree
// (counting sort, 64 bins) so gather waves get uniform-degree nodes.
__global__ __launch_bounds__(1024) void csrbuild_kernel(
        const unsigned* __restrict__ packed, const unsigned* __restrict__ bbase,
        uint2* __restrict__ desc, unsigned char* __restrict__ degu8,
        int* __restrict__ csr, int N) {
    __shared__ unsigned cnt[BNODES];   // degrees (preserved)
    __shared__ unsigned pref[BNODES];  // exclusive prefix -> later csr cursor
    __shared__ unsigned stmp[1024];
    __shared__ unsigned hd[64];        // degree-bin hist -> cursor
    int b = blockIdx.x, t = threadIdx.x;
    cnt[t] = 0u; cnt[t + 1024] = 0u;
    if (t < 64) hd[t] = 0u;
    __syncthreads();
    unsigned base = bbase[b], end = bbase[b + 1];
    for (unsigned e = base + t; e < end; e += 1024)
        atomicAdd(&cnt[packed[e] & (BNODES - 1)], 1u);
    __syncthreads();
    unsigned a0 = cnt[2 * t], a1 = cnt[2 * t + 1];
    unsigned tsum = a0 + a1;
    stmp[t] = tsum; __syncthreads();
    for (int off = 1; off < 1024; off <<= 1) {
        unsigned a = (t >= off) ? stmp[t - off] : 0u;
        __syncthreads();
        stmp[t] += a;
        __syncthreads();
    }
    unsigned pre = stmp[t] - tsum;
    pref[2 * t] = pre; pref[2 * t + 1] = pre + a0;
    int node0 = b << BUCKET_BITS;
    // init desc slots invalid; degree-bin histogram
    desc[node0 + t]        = make_uint2(0u, 0xFFFFFFFFu);
    desc[node0 + t + 1024] = make_uint2(0u, 0xFFFFFFFFu);
    if (node0 + t < N)        atomicAdd(&hd[umin(cnt[t], 63u)], 1u);
    if (node0 + t + 1024 < N) atomicAdd(&hd[umin(cnt[t + 1024], 63u)], 1u);
    __syncthreads();
    if (t == 0) {  // tiny serial exclusive scan of 64 degree bins
        unsigned run = 0;
        for (int q = 0; q < 64; ++q) { unsigned c = hd[q]; hd[q] = run; run += c; }
    }
    __syncthreads();
    // scatter descriptors in degree-sorted order + per-node degree byte
    for (int k = t; k < BNODES; k += 1024) {
        int i = node0 + k;
        if (i < N) {
            unsigned deg = cnt[k];
            unsigned pos = atomicAdd(&hd[umin(deg, 63u)], 1u);
            desc[node0 + pos] = make_uint2(base + pref[k],
                                           ((unsigned)i << 13) | umin(deg, 8191u));
            degu8[i] = (unsigned char)umin(deg, 255u);
        }
    }
    __syncthreads();
    // scatter src ids into csr (pref doubles as cursor)
    for (unsigned e = base + t; e < end; e += 1024) {
        unsigned p = packed[e];
        unsigned dl = p & (BNODES - 1);
        unsigned pos = base + atomicAdd(&pref[dl], 1u);
        csr[pos] = (int)(p >> BUCKET_BITS);
    }
}

// ---------------- padded, prescaled x copy: xp[i] = 64B row = dinv[i]*x[i] ----
__global__ void padx_kernel(const float* __restrict__ x, const unsigned char* __restrict__ degu8,
                            float* __restrict__ xp, int N) {
    int i = blockIdx.x * 256 + threadIdx.x;
    if (i >= N) return;
    float di = rsqrtf((float)degu8[i] + 1.0f);
    const float2* xr = reinterpret_cast<const float2*>(x + (size_t)i * IN_DIM);
    float2 t0 = xr[0], t1 = xr[1], t2 = xr[2], t3 = xr[3], t4 = xr[4];
    float4* op = reinterpret_cast<float4*>(xp + ((size_t)i << 4));
    op[0] = make_float4(t0.x * di, t0.y * di, t1.x * di, t1.y * di);
    op[1] = make_float4(t2.x * di, t2.y * di, t3.x * di, t3.y * di);
    op[2] = make_float4(t4.x * di, t4.y * di, 0.0f, 0.0f);
    op[3] = make_float4(0.0f, 0.0f, 0.0f, 0.0f);
}

// ---------------- layer-1: desc-driven register gather + fused MLP ------------
__global__ __launch_bounds__(256) void gather1_kernel(
        const int* __restrict__ csr, const uint2* __restrict__ desc,
        const float* __restrict__ xp,
        const float* __restrict__ W1, const float* __restrict__ b1,
        const float* __restrict__ W2, float2* __restrict__ ts) {
    __shared__ float sW1[IN_DIM * HID_DIM];
    __shared__ float sb1[HID_DIM];
    __shared__ float sW2[HID_DIM * OUT_DIM];
    for (int k = threadIdx.x; k < IN_DIM * HID_DIM; k += 256) sW1[k] = W1[k];
    if (threadIdx.x < HID_DIM) sb1[threadIdx.x] = b1[threadIdx.x];
    if (threadIdx.x < HID_DIM * OUT_DIM) sW2[threadIdx.x] = W2[threadIdx.x];
    __syncthreads();

    int g = blockIdx.x * 256 + threadIdx.x;
    uint2 dsc = desc[g];
    if (dsc.y == 0xFFFFFFFFu) return;
    unsigned e = dsc.x;
    unsigned deg = dsc.y & 8191u;
    unsigned node = dsc.y >> 13;
    unsigned end = e + deg;
    float di = rsqrtf((float)deg + 1.0f);

    float v[IN_DIM];
    {
        const float4* xi = reinterpret_cast<const float4*>(xp + ((size_t)node << 4));
        float4 a = xi[0], bq = xi[1];
        float2 c = reinterpret_cast<const float2*>(xi)[4];
        v[0] = a.x; v[1] = a.y; v[2] = a.z; v[3] = a.w;
        v[4] = bq.x; v[5] = bq.y; v[6] = bq.z; v[7] = bq.w;
        v[8] = c.x; v[9] = c.y;
    }
    while (e + 1 < end) {  // two independent line-gathers in flight
        int s0 = csr[e], s1 = csr[e + 1];
        const float4* r0 = reinterpret_cast<const float4*>(xp + ((size_t)s0 << 4));
        const float4* r1 = reinterpret_cast<const float4*>(xp + ((size_t)s1 << 4));
        float4 a0 = r0[0], q0 = r0[1];
        float2 c0 = reinterpret_cast<const float2*>(r0)[4];
        float4 a1 = r1[0], q1 = r1[1];
        float2 c1 = reinterpret_cast<const float2*>(r1)[4];
        v[0] += a0.x + a1.x; v[1] += a0.y + a1.y; v[2] += a0.z + a1.z; v[3] += a0.w + a1.w;
        v[4] += q0.x + q1.x; v[5] += q0.y + q1.y; v[6] += q0.z + q1.z; v[7] += q0.w + q1.w;
        v[8] += c0.x + c1.x; v[9] += c0.y + c1.y;
        e += 2;
    }
    if (e < end) {
        int s = csr[e];
        const float4* r = reinterpret_cast<const float4*>(xp + ((size_t)s << 4));
        float4 a = r[0], q = r[1];
        float2 c = reinterpret_cast<const float2*>(r)[4];
        v[0] += a.x; v[1] += a.y; v[2] += a.z; v[3] += a.w;
        v[4] += q.x; v[5] += q.y; v[6] += q.z; v[7] += q.w;
        v[8] += c.x; v[9] += c.y;
    }
    #pragma unroll
    for (int k = 0; k < IN_DIM; ++k) v[k] *= di;
    float t0 = 0.0f, t1 = 0.0f;
    #pragma unroll
    for (int j = 0; j < HID_DIM; ++j) {
        float hh = sb1[j];
        #pragma unroll
        for (int q = 0; q < IN_DIM; ++q) hh = fmaf(v[q], sW1[q * HID_DIM + j], hh);
        hh = fmaxf(hh, 0.0f);
        t0 = fmaf(hh, sW2[2 * j + 0], t0);
        t1 = fmaf(hh, sW2[2 * j + 1], t1);
    }
    ts[node] = make_float2(t0 * di, t1 * di);
}

// ---------------- layer-2: desc-driven gather + bias + log_softmax ------------
__global__ __launch_bounds__(256) void gather2_kernel(
        const int* __restrict__ csr, const uint2* __restrict__ desc,
        const float2* __restrict__ ts, const float* __restrict__ b2,
        float2* __restrict__ out) {
    int g = blockIdx.x * 256 + threadIdx.x;
    uint2 dsc = desc[g];
    if (dsc.y == 0xFFFFFFFFu) return;
    unsigned e = dsc.x;
    unsigned deg = dsc.y & 8191u;
    unsigned node = dsc.y >> 13;
    unsigned end = e + deg;
    float di = rsqrtf((float)deg + 1.0f);
    float2 acc = ts[node];  // self-loop (already carries dinv factor)
    while (e + 1 < end) {
        int s0 = csr[e], s1 = csr[e + 1];
        float2 t0 = ts[s0], t1 = ts[s1];
        acc.x += t0.x + t1.x; acc.y += t0.y + t1.y;
        e += 2;
    }
    if (e < end) {
        float2 tv = ts[csr[e]];
        acc.x += tv.x; acc.y += tv.y;
    }
    float a0 = di * acc.x + b2[0];
    float a1 = di * acc.y + b2[1];
    float m = fmaxf(a0, a1);
    float lse = m + logf(expf(a0 - m) + expf(a1 - m));
    out[node] = make_float2(a0 - lse, a1 - lse);
}

extern "C" void kernel_launch(void* const* d_in, const int* in_sizes, int n_in,
                              void* d_out, int out_size, void* d_ws, size_t ws_size,
                              hipStream_t stream) {
    const float* x  = (const float*)d_in[0];
    const int*   ei = (const int*)d_in[1];   // [2, E]: src row then dst row
    const float* W1 = (const float*)d_in[2];
    const float* b1 = (const float*)d_in[3];
    const float* W2 = (const float*)d_in[4];
    const float* b2 = (const float*)d_in[5];
    float2* out = (float2*)d_out;

    const int* src = ei;
    const int* dst = ei + N_EDGES;

    // workspace (u32 units): counters[1024 pad] | desc[NSLOT uint2] | ts[2N] |
    // packed[8M] (xp aliases after csrbuild) | csr[8M] | degu8[500K bytes] ~= 72.5 MB
    unsigned* bcount   = (unsigned*)d_ws;
    unsigned* bbase    = bcount + NBP;
    unsigned* bcursor  = bbase + NBP + 1;
    uint2*    desc     = (uint2*)((unsigned*)d_ws + 1024);
    float2*   ts       = (float2*)(desc + NSLOT);
    unsigned* packed   = (unsigned*)(ts + N_NODES);
    int*      csr      = (int*)(packed + N_EDGES);
    unsigned char* degu8 = (unsigned char*)(csr + N_EDGES);
    float*    xp       = (float*)packed;     // reuse after csrbuild

    zero_small_kernel<<<1, NBP, 0, stream>>>(bcount);
    hist_kernel<<<1024, NBP, 0, stream>>>((const int4*)dst, bcount, N_EDGES / 4);
    scan_kernel<<<1, NBP, 0, stream>>>(bcount, bbase, bcursor);
    partition_kernel<<<NTILES, PART_TPB, 0, stream>>>(src, dst, bcursor, packed, N_EDGES);
    csrbuild_kernel<<<NB, 1024, 0, stream>>>(packed, bbase, desc, degu8, csr, N_NODES);
    padx_kernel<<<(N_NODES + 255) / 256, 256, 0, stream>>>(x, degu8, xp, N_NODES);
    gather1_kernel<<<NSLOT / 256, 256, 0, stream>>>(csr, desc, xp, W1, b1, W2, ts);
    gather2_kernel<<<NSLOT / 256, 256, 0, stream>>>(csr, desc, ts, b2, out);
}

// Round 12
// 537.556 us; speedup vs baseline: 1.3704x; 1.3704x over previous
//
#include <hip/hip_runtime.h>
#include <math.h>

constexpr int N_NODES = 500000;
constexpr int N_EDGES = 8000000;
constexpr int IN_DIM = 10, HID_DIM = 35, OUT_DIM = 2;

constexpr int BUCKET_BITS = 11;                       // 2048 dst-nodes per bucket
constexpr int BNODES = 1 << BUCKET_BITS;              // 2048
constexpr int NB = (N_NODES + BNODES - 1) / BNODES;   // 245 buckets
constexpr int NBP = 256;                              // padded
constexpr unsigned CAP = 34816;                       // bucket region capacity (mean 32768 + 11 sigma)

constexpr int PART_TPB = 1024;
constexpr int EPT = 32;
constexpr int TILE = PART_TPB * EPT;                  // 32768
constexpr int NTILES = (N_EDGES + TILE - 1) / TILE;   // 245

// ---------------- init per-bucket cursors to region bases ----------------
__global__ void initcur_kernel(unsigned* __restrict__ cursor) {
    cursor[threadIdx.x] = (unsigned)threadIdx.x * CAP;
}

// ---------------- partition: pack (src<<11 | dst&2047) into CAP regions -------
__global__ __launch_bounds__(PART_TPB) void partition_kernel(
        const int* __restrict__ src, const int* __restrict__ dst,
        unsigned* __restrict__ cursor, unsigned* __restrict__ packed, int E) {
    __shared__ unsigned h[NBP], base[NBP], c2[NBP];
    int t = threadIdx.x;
    for (int k = t; k < NBP; k += PART_TPB) { h[k] = 0u; c2[k] = 0u; }
    __syncthreads();
    int tile0 = blockIdx.x * TILE;
    int d[EPT];
    #pragma unroll
    for (int q = 0; q < EPT; ++q) {
        int e = tile0 + q * PART_TPB + t;
        d[q] = (e < E) ? dst[e] : -1;
        if (d[q] >= 0) atomicAdd(&h[d[q] >> BUCKET_BITS], 1u);
    }
    __syncthreads();
    for (int k = t; k < NBP; k += PART_TPB)
        if (h[k]) base[k] = atomicAdd(&cursor[k], h[k]);
    __syncthreads();
    #pragma unroll
    for (int q = 0; q < EPT; ++q) {
        int e = tile0 + q * PART_TPB + t;
        if (d[q] >= 0) {
            int b = d[q] >> BUCKET_BITS;
            unsigned pos = base[b] + atomicAdd(&c2[b], 1u);
            packed[pos] = ((unsigned)src[e] << BUCKET_BITS) | (unsigned)(d[q] & (BNODES - 1));
        }
    }
}

// ---------------- per-bucket CSR build + rowstart + degree byte ---------------
__global__ __launch_bounds__(1024) void csrbuild_kernel(
        const unsigned* __restrict__ packed, const unsigned* __restrict__ cursor,
        unsigned* __restrict__ rowstart, unsigned char* __restrict__ degu8,
        int* __restrict__ csr, int N) {
    __shared__ unsigned cnt[BNODES];   // degrees
    __shared__ unsigned pref[BNODES];  // prefix -> later csr scatter cursor
    __shared__ unsigned stmp[1024];
    int b = blockIdx.x, t = threadIdx.x;
    cnt[t] = 0u; cnt[t + 1024] = 0u;
    __syncthreads();
    unsigned base = (unsigned)b * CAP, end = cursor[b];
    for (unsigned e = base + t; e < end; e += 1024)
        atomicAdd(&cnt[packed[e] & (BNODES - 1)], 1u);
    __syncthreads();
    unsigned a0 = cnt[2 * t], a1 = cnt[2 * t + 1];
    unsigned tsum = a0 + a1;
    stmp[t] = tsum; __syncthreads();
    for (int off = 1; off < 1024; off <<= 1) {
        unsigned a = (t >= off) ? stmp[t - off] : 0u;
        __syncthreads();
        stmp[t] += a;
        __syncthreads();
    }
    unsigned pre = stmp[t] - tsum;
    pref[2 * t] = pre; pref[2 * t + 1] = pre + a0;
    __syncthreads();
    int node0 = b << BUCKET_BITS;
    for (int k = t; k < BNODES; k += 1024) {
        int i = node0 + k;
        if (i < N) {
            rowstart[i] = base + pref[k];
            degu8[i] = (unsigned char)(cnt[k] < 255u ? cnt[k] : 255u);
        }
    }
    __syncthreads();
    for (unsigned e = base + t; e < end; e += 1024) {
        unsigned p = packed[e];
        unsigned dl = p & (BNODES - 1);
        unsigned pos = base + atomicAdd(&pref[dl], 1u);
        csr[pos] = (int)(p >> BUCKET_BITS);
    }
}

// ---------------- padded, prescaled x copy: xp[i] = 64B row = dinv[i]*x[i] ----
__global__ void padx_kernel(const float* __restrict__ x, const unsigned char* __restrict__ degu8,
                            float* __restrict__ xp, int N) {
    int i = blockIdx.x * 256 + threadIdx.x;
    if (i >= N) return;
    float di = rsqrtf((float)degu8[i] + 1.0f);
    const float2* xr = reinterpret_cast<const float2*>(x + (size_t)i * IN_DIM);
    float2 t0 = xr[0], t1 = xr[1], t2 = xr[2], t3 = xr[3], t4 = xr[4];
    float4* op = reinterpret_cast<float4*>(xp + ((size_t)i << 4));
    op[0] = make_float4(t0.x * di, t0.y * di, t1.x * di, t1.y * di);
    op[1] = make_float4(t2.x * di, t2.y * di, t3.x * di, t3.y * di);
    op[2] = make_float4(t4.x * di, t4.y * di, 0.0f, 0.0f);
    op[3] = make_float4(0.0f, 0.0f, 0.0f, 0.0f);
}

// ---------------- layer-1: register gather (1 line/edge, unroll-2) + MLP ------
__global__ __launch_bounds__(256) void gather1_kernel(
        const int* __restrict__ csr, const unsigned* __restrict__ rowstart,
        const unsigned char* __restrict__ degu8, const float* __restrict__ xp,
        const float* __restrict__ W1, const float* __restrict__ b1,
        const float* __restrict__ W2, float2* __restrict__ ts, int N) {
    __shared__ float sW1[IN_DIM * HID_DIM];
    __shared__ float sb1[HID_DIM];
    __shared__ float sW2[HID_DIM * OUT_DIM];
    for (int k = threadIdx.x; k < IN_DIM * HID_DIM; k += 256) sW1[k] = W1[k];
    if (threadIdx.x < HID_DIM) sb1[threadIdx.x] = b1[threadIdx.x];
    if (threadIdx.x < HID_DIM * OUT_DIM) sW2[threadIdx.x] = W2[threadIdx.x];
    __syncthreads();

    int i = blockIdx.x * 256 + threadIdx.x;
    if (i >= N) return;
    unsigned e = rowstart[i];
    unsigned deg = degu8[i];
    unsigned end = e + deg;
    float di = rsqrtf((float)deg + 1.0f);

    float v[IN_DIM];
    {
        const float4* xi = reinterpret_cast<const float4*>(xp + ((size_t)i << 4));
        float4 a = xi[0], bq = xi[1];
        float2 c = reinterpret_cast<const float2*>(xi)[4];
        v[0] = a.x; v[1] = a.y; v[2] = a.z; v[3] = a.w;
        v[4] = bq.x; v[5] = bq.y; v[6] = bq.z; v[7] = bq.w;
        v[8] = c.x; v[9] = c.y;
    }
    while (e + 1 < end) {  // two independent line-gathers in flight
        int s0 = csr[e], s1 = csr[e + 1];
        const float4* r0 = reinterpret_cast<const float4*>(xp + ((size_t)s0 << 4));
        const float4* r1 = reinterpret_cast<const float4*>(xp + ((size_t)s1 << 4));
        float4 a0 = r0[0], q0 = r0[1];
        float2 c0 = reinterpret_cast<const float2*>(r0)[4];
        float4 a1 = r1[0], q1 = r1[1];
        float2 c1 = reinterpret_cast<const float2*>(r1)[4];
        v[0] += a0.x + a1.x; v[1] += a0.y + a1.y; v[2] += a0.z + a1.z; v[3] += a0.w + a1.w;
        v[4] += q0.x + q1.x; v[5] += q0.y + q1.y; v[6] += q0.z + q1.z; v[7] += q0.w + q1.w;
        v[8] += c0.x + c1.x; v[9] += c0.y + c1.y;
        e += 2;
    }
    if (e < end) {
        int s = csr[e];
        const float4* r = reinterpret_cast<const float4*>(xp + ((size_t)s << 4));
        float4 a = r[0], q = r[1];
        float2 c = reinterpret_cast<const float2*>(r)[4];
        v[0] += a.x; v[1] += a.y; v[2] += a.z; v[3] += a.w;
        v[4] += q.x; v[5] += q.y; v[6] += q.z; v[7] += q.w;
        v[8] += c.x; v[9] += c.y;
    }
    #pragma unroll
    for (int k = 0; k < IN_DIM; ++k) v[k] *= di;
    float t0 = 0.0f, t1 = 0.0f;
    #pragma unroll
    for (int j = 0; j < HID_DIM; ++j) {
        float hh = sb1[j];
        #pragma unroll
        for (int q = 0; q < IN_DIM; ++q) hh = fmaf(v[q], sW1[q * HID_DIM + j], hh);
        hh = fmaxf(hh, 0.0f);
        t0 = fmaf(hh, sW2[2 * j + 0], t0);
        t1 = fmaf(hh, sW2[2 * j + 1], t1);
    }
    ts[i] = make_float2(t0 * di, t1 * di);
}

// ---------------- layer-2: register gather (unroll-2) + log_softmax -----------
__global__ __launch_bounds__(256) void gather2_kernel(
        const int* __restrict__ csr, const unsigned* __restrict__ rowstart,
        const unsigned char* __restrict__ degu8, const float2* __restrict__ ts,
        const float* __restrict__ b2, float2* __restrict__ out, int N) {
    int i = blockIdx.x * 256 + threadIdx.x;
    if (i >= N) return;
    unsigned e = rowstart[i];
    unsigned deg = degu8[i];
    unsigned end = e + deg;
    float di = rsqrtf((float)deg + 1.0f);
    float2 acc = ts[i];  // self-loop (already carries dinv factor)
    while (e + 1 < end) {
        int s0 = csr[e], s1 = csr[e + 1];
        float2 t0 = ts[s0], t1 = ts[s1];
        acc.x += t0.x + t1.x; acc.y += t0.y + t1.y;
        e += 2;
    }
    if (e < end) {
        float2 tv = ts[csr[e]];
        acc.x += tv.x; acc.y += tv.y;
    }
    float a0 = di * acc.x + b2[0];
    float a1 = di * acc.y + b2[1];
    float m = fmaxf(a0, a1);
    float lse = m + logf(expf(a0 - m) + expf(a1 - m));
    out[i] = make_float2(a0 - lse, a1 - lse);
}

extern "C" void kernel_launch(void* const* d_in, const int* in_sizes, int n_in,
                              void* d_out, int out_size, void* d_ws, size_t ws_size,
                              hipStream_t stream) {
    const float* x  = (const float*)d_in[0];
    const int*   ei = (const int*)d_in[1];   // [2, E]: src row then dst row
    const float* W1 = (const float*)d_in[2];
    const float* b1 = (const float*)d_in[3];
    const float* W2 = (const float*)d_in[4];
    const float* b2 = (const float*)d_in[5];
    float2* out = (float2*)d_out;

    const int* src = ei;
    const int* dst = ei + N_EDGES;

    // workspace (u32 units): cursor[256] | rowstart[N] | degu8[N bytes] | ts[2N]
    // | packed[245*CAP] (xp aliases after csrbuild) | csr[245*CAP]   ~= 75 MB
    unsigned* cursor   = (unsigned*)d_ws;
    unsigned* rowstart = cursor + NBP;
    unsigned char* degu8 = (unsigned char*)(rowstart + N_NODES);
    float2*   ts       = (float2*)(degu8 + ((N_NODES + 127) & ~127));
    unsigned* packed   = (unsigned*)(ts + N_NODES);
    int*      csr      = (int*)(packed + (size_t)NB * CAP);
    float*    xp       = (float*)packed;     // reuse after csrbuild

    initcur_kernel<<<1, NBP, 0, stream>>>(cursor);
    partition_kernel<<<NTILES, PART_TPB, 0, stream>>>(src, dst, cursor, packed, N_EDGES);
    csrbuild_kernel<<<NB, 1024, 0, stream>>>(packed, cursor, rowstart, degu8, csr, N_NODES);
    padx_kernel<<<(N_NODES + 255) / 256, 256, 0, stream>>>(x, degu8, xp, N_NODES);
    gather1_kernel<<<(N_NODES + 255) / 256, 256, 0, stream>>>(csr, rowstart, degu8, xp, W1, b1, W2, ts, N_NODES);
    gather2_kernel<<<(N_NODES + 255) / 256, 256, 0, stream>>>(csr, rowstart, degu8, ts, b2, out, N_NODES);
}